// Round 14
// baseline (461.256 us; speedup 1.0000x reference)
//
#include <hip/hip_runtime.h>
#include <hip/hip_bf16.h>

#define N_NODES 100000
#define N_EDGES 1600000
#define IN_CH 50
#define NPB 512                                   // nodes per bucket (dst >> 9)
#define NB ((N_NODES + NPB - 1) / NPB)            // 196 buckets
#define CAPLOG 14                                 // 16384 slots/bucket (max ~8.6K used)
#define EPB 4096
#define NBLK_A ((N_EDGES + EPB - 1) / EPB)        // 391 blocks
#define PAD_BLOCKS ((N_NODES * 64) / 256)         // 25000

typedef float v2f __attribute__((ext_vector_type(2)));

// packed dual-fp32 fma: acc = f * w + acc (two lanes-of-pair at once)
__device__ __forceinline__ void pk_fma(v2f& acc, v2f f, float w) {
    v2f w2; w2.x = w; w2.y = w;
    asm volatile("v_pk_fma_f32 %0, %1, %2, %0" : "+v"(acc) : "v"(f), "v"(w2));
}

// ---- 1. bin edges into fixed-capacity buckets (+ extra blocks: pad x->xb bf16) ----
__global__ __launch_bounds__(256) void bin_pad_kernel(
    const int* __restrict__ src, const int* __restrict__ dst,
    int* __restrict__ cursor_rel, unsigned* __restrict__ binned,
    const float* __restrict__ x, unsigned short* __restrict__ xb) {
    if (blockIdx.x >= NBLK_A) {                    // pad lane
        int t = (blockIdx.x - NBLK_A) * 256 + threadIdx.x;   // < N_NODES*64
        int n = t >> 6, c = t & 63;
        float v = (c < IN_CH) ? x[n * IN_CH + c] : 0.0f;
        __hip_bfloat16 hb = __float2bfloat16(v);
        xb[t] = *(unsigned short*)&hb;
        return;
    }
    __shared__ int bc[NB];
    __shared__ int boff[NB];
    int t = threadIdx.x;
    if (t < NB) bc[t] = 0;
    __syncthreads();
    int e0 = blockIdx.x * EPB;
    int e1 = min(e0 + EPB, N_EDGES);
    for (int i = e0 + t; i < e1; i += 256)
        atomicAdd(&bc[dst[i] >> 9], 1);
    __syncthreads();
    if (t < NB) {
        int v = bc[t];
        int rel = v ? atomicAdd(&cursor_rel[t], v) : 0;
        boff[t] = (t << CAPLOG) + rel;
        bc[t] = 0;                                 // reuse as local cursor
    }
    __syncthreads();
    for (int i = e0 + t; i < e1; i += 256) {
        int d = dst[i];
        int b = d >> 9;
        int k = atomicAdd(&bc[b], 1);
        binned[boff[b] + k] = ((unsigned)(d & 511) << 17) | (unsigned)src[i];
    }
}

// ---- 2. per-bucket fine sort (u32 payload) -> cnt, row_start, csr_src ----
__global__ __launch_bounds__(256) void bucket_fine(
    const unsigned* __restrict__ binned, const int* __restrict__ cursor_rel,
    int* __restrict__ cnt, int* __restrict__ row_start, int* __restrict__ csr_src) {
    __shared__ int lcnt[NPB];
    __shared__ int lofs[NPB];
    __shared__ int sc[256];
    int t = threadIdx.x;
    int b = blockIdx.x;
    int nbase = b * NPB;
    int bbase = b << CAPLOG;
    int ecnt  = cursor_rel[b];
    lcnt[t] = 0; lcnt[t + 256] = 0;
    __syncthreads();
    for (int i = t; i < ecnt; i += 256)
        atomicAdd(&lcnt[(binned[bbase + i] >> 17) & 511], 1);
    __syncthreads();
    int v0 = lcnt[2 * t], v1 = lcnt[2 * t + 1];
    int pair = v0 + v1;
    sc[t] = pair;
    __syncthreads();
    for (int off = 1; off < 256; off <<= 1) {
        int tmp = (t >= off) ? sc[t - off] : 0;
        __syncthreads();
        sc[t] += tmp;
        __syncthreads();
    }
    int excl = sc[t] - pair;
    lofs[2 * t] = excl;
    lofs[2 * t + 1] = excl + v0;
    __syncthreads();
    {
        int n0 = nbase + t;
        if (n0 < N_NODES) { cnt[n0] = lcnt[t]; row_start[n0] = bbase + lofs[t]; }
        int n1 = nbase + t + 256;
        if (n1 < N_NODES) { cnt[n1] = lcnt[t + 256]; row_start[n1] = bbase + lofs[t + 256]; }
    }
    __syncthreads();
    for (int i = t; i < ecnt; i += 256) {
        unsigned p = binned[bbase + i];
        int d = (int)((p >> 17) & 511);
        int k = atomicAdd(&lofs[d], 1);
        csr_src[bbase + k] = (int)(p & 0x1FFFFu);
    }
}

// unpack 8 bf16 from uint4, predicated fma into acc[0..8)
__device__ __forceinline__ void upadd8(float* a, uint4 v, float p) {
    a[0] = fmaf(p, __uint_as_float(v.x << 16), a[0]);
    a[1] = fmaf(p, __uint_as_float(v.x & 0xffff0000u), a[1]);
    a[2] = fmaf(p, __uint_as_float(v.y << 16), a[2]);
    a[3] = fmaf(p, __uint_as_float(v.y & 0xffff0000u), a[3]);
    a[4] = fmaf(p, __uint_as_float(v.z << 16), a[4]);
    a[5] = fmaf(p, __uint_as_float(v.z & 0xffff0000u), a[5]);
    a[6] = fmaf(p, __uint_as_float(v.w << 16), a[6]);
    a[7] = fmaf(p, __uint_as_float(v.w & 0xffff0000u), a[7]);
}

// wave-local LDS fence: LDS ops of one wave complete in order; no block barrier.
#define WAVE_LDS_FENCE() __asm__ volatile("s_waitcnt lgkmcnt(0)" ::: "memory")

// Gather-mean of 4 nodes per wave, chains interleaved (proven R7/R10 shape).
__device__ __forceinline__ void gather4(
    const unsigned short* __restrict__ featb, const int* __restrict__ csr_src,
    const int* __restrict__ row_start, const int* __restrict__ cnt,
    int nb, int lane, float acc[4][8]) {
    int g  = lane >> 3;
    int cw = (lane & 7) * 8;
    int start[4], deg[4], sv[4];
    int dmax = 0;
    #pragma unroll
    for (int i = 0; i < 4; ++i) {
        start[i] = row_start[nb + i];
        deg[i]   = cnt[nb + i];
        dmax = max(dmax, deg[i]);
        #pragma unroll
        for (int c = 0; c < 8; ++c) acc[i][c] = 0.f;
    }
    #pragma unroll
    for (int i = 0; i < 4; ++i)
        sv[i] = (lane < deg[i]) ? csr_src[start[i] + lane] : 0;

    #pragma unroll
    for (int cb = 0; cb < 64; cb += 16) {
        if (cb >= dmax) break;                 // wave-uniform
        #pragma unroll
        for (int i = 0; i < 4; ++i) {
            int rem = deg[i] - cb;
            if (rem > 0) {                     // wave-uniform
                int s0 = __shfl(sv[i], cb + g);
                int s1 = __shfl(sv[i], cb + 8 + g);
                float p0 = (g < rem) ? 1.f : 0.f;
                float p1 = (g + 8 < rem) ? 1.f : 0.f;
                uint4 v0 = *(const uint4*)(featb + s0 * 64 + cw);
                uint4 v1 = *(const uint4*)(featb + s1 * 64 + cw);
                upadd8(acc[i], v0, p0);
                upadd8(acc[i], v1, p1);
            }
        }
    }
    if (dmax > 64) {                           // rare tail
        for (int i = 0; i < 4; ++i) {
            for (int c0 = 64; c0 < deg[i]; c0 += 64) {
                int rem = deg[i] - c0; if (rem > 64) rem = 64;
                int sx = (lane < rem) ? csr_src[start[i] + c0 + lane] : 0;
                for (int cb = 0; cb < rem; cb += 16) {
                    int s0 = __shfl(sx, cb + g);
                    int s1 = __shfl(sx, cb + 8 + g);
                    float p0 = (cb + g < rem) ? 1.f : 0.f;
                    float p1 = (cb + 8 + g < rem) ? 1.f : 0.f;
                    uint4 v0 = *(const uint4*)(featb + s0 * 64 + cw);
                    uint4 v1 = *(const uint4*)(featb + s1 * 64 + cw);
                    upadd8(acc[i], v0, p0);
                    upadd8(acc[i], v1, p1);
                }
            }
        }
    }
    #pragma unroll
    for (int i = 0; i < 4; ++i) {
        float inv = 1.0f / fmaxf((float)deg[i], 1.0f);
        #pragma unroll
        for (int c = 0; c < 8; ++c) {
            float t = acc[i][c];
            t += __shfl_xor(t, 8);
            t += __shfl_xor(t, 16);
            t += __shfl_xor(t, 32);
            acc[i][c] = t * inv;
        }
    }
}

__device__ __forceinline__ float bf16u(unsigned short u) {
    return __uint_as_float(((unsigned)u) << 16);
}

// ---- 3. layer 1: gather(xb) + node-interleaved LDS + pk_fma GEMM(100x64) ----
// featP[w][k][i]: k<50 self-ch k, k>=50 mean-ch (k-50); node i inner (float4 rows).
__global__ __launch_bounds__(256) void layer1_fused(
    const unsigned short* __restrict__ xb,
    const int* __restrict__ csr_src, const int* __restrict__ row_start,
    const int* __restrict__ cnt, const float* __restrict__ W1,
    const float* __restrict__ b1, unsigned short* __restrict__ h1b) {
    int wv   = threadIdx.x >> 6;
    int lane = threadIdx.x & 63;
    int nb   = (blockIdx.x * 4 + wv) * 4;      // N_NODES % 16 == 0

    float acc[4][8];
    gather4(xb, csr_src, row_start, cnt, nb, lane, acc);

    __shared__ __align__(16) float featP[4][2 * IN_CH][4];   // 6.4 KB
    if (lane < IN_CH) {
        float s0 = bf16u(xb[((nb + 0) << 6) + lane]);
        float s1 = bf16u(xb[((nb + 1) << 6) + lane]);
        float s2 = bf16u(xb[((nb + 2) << 6) + lane]);
        float s3 = bf16u(xb[((nb + 3) << 6) + lane]);
        *(float4*)&featP[wv][lane][0] = make_float4(s0, s1, s2, s3);
    }
    if (lane < 8) {
        #pragma unroll
        for (int c = 0; c < 8; ++c) {
            int ch = lane * 8 + c;
            if (ch < IN_CH)
                *(float4*)&featP[wv][IN_CH + ch][0] =
                    make_float4(acc[0][c], acc[1][c], acc[2][c], acc[3][c]);
        }
    }
    WAVE_LDS_FENCE();

    float bb = b1[lane];
    v2f a01; a01.x = bb; a01.y = bb;
    v2f a23 = a01;
    #pragma unroll 2
    for (int k = 0; k < 2 * IN_CH; ++k) {
        float w = W1[k * 64 + lane];           // lanes coalesced, reused x4 via pk
        v2f f01 = *(const v2f*)&featP[wv][k][0];
        v2f f23 = *(const v2f*)&featP[wv][k][2];
        pk_fma(a01, f01, w);
        pk_fma(a23, f23, w);
    }
    float ao[4] = {a01.x, a01.y, a23.x, a23.y};
    #pragma unroll
    for (int i = 0; i < 4; ++i) {
        float r = fmaxf(ao[i], 0.f);
        __hip_bfloat16 hb = __float2bfloat16(r);
        h1b[((nb + i) << 6) + lane] = *(unsigned short*)&hb;
    }
}

// ---- 4. layers 2+3: gather(h1b) + interleaved LDS (slots [0,2,1,3]) + pk_fma ----
__global__ __launch_bounds__(256) void layer23_fused(
    const unsigned short* __restrict__ h1b,
    const int* __restrict__ csr_src, const int* __restrict__ row_start,
    const int* __restrict__ cnt, const float* __restrict__ W2,
    const float* __restrict__ b2, const float* __restrict__ W3,
    const float* __restrict__ b3, float* __restrict__ out) {
    int wv   = threadIdx.x >> 6;
    int lane = threadIdx.x & 63;
    int nb   = (blockIdx.x * 4 + wv) * 4;

    float acc[4][8];
    gather4(h1b, csr_src, row_start, cnt, nb, lane, acc);

    // featP[w][k][slot]; slot order = nodes [0,2,1,3] so half-wave pairs are adjacent.
    __shared__ __align__(16) float featP[4][128][4];         // 8 KB
    {
        float s0 = bf16u(h1b[((nb + 0) << 6) + lane]);
        float s1 = bf16u(h1b[((nb + 1) << 6) + lane]);
        float s2 = bf16u(h1b[((nb + 2) << 6) + lane]);
        float s3 = bf16u(h1b[((nb + 3) << 6) + lane]);
        *(float4*)&featP[wv][lane][0] = make_float4(s0, s2, s1, s3);
    }
    if (lane < 8) {
        #pragma unroll
        for (int c = 0; c < 8; ++c) {
            int k = 64 + lane * 8 + c;
            *(float4*)&featP[wv][k][0] =
                make_float4(acc[0][c], acc[2][c], acc[1][c], acc[3][c]);
        }
    }
    WAVE_LDS_FENCE();

    int hh = lane >> 5;                        // half-wave id: nodes nb+hh, nb+2+hh
    int j  = lane & 31;
    float bb = b2[j];
    v2f ap; ap.x = bb; ap.y = bb;              // (node nb+hh, node nb+2+hh)
    #pragma unroll 4
    for (int k = 0; k < 128; ++k) {
        float w = W2[k * 32 + j];
        v2f f = *(const v2f*)&featP[wv][k][hh * 2];
        pk_fma(ap, f, w);
    }
    float w3 = W3[j];
    float c3 = b3[0];
    float v0 = fmaxf(ap.x, 0.f) * w3;
    float v1 = fmaxf(ap.y, 0.f) * w3;
    #pragma unroll
    for (int off = 1; off <= 16; off <<= 1) {
        v0 += __shfl_xor(v0, off);
        v1 += __shfl_xor(v1, off);
    }
    if (j == 0) {
        out[nb + hh]     = v0 + c3;
        out[nb + 2 + hh] = v1 + c3;
    }
}

extern "C" void kernel_launch(void* const* d_in, const int* in_sizes, int n_in,
                              void* d_out, int out_size, void* d_ws, size_t ws_size,
                              hipStream_t stream) {
    const float* x   = (const float*)d_in[0];
    const int*   ei  = (const int*)d_in[1];
    const int*   src = ei;
    const int*   dst = ei + N_EDGES;
    const float* W1  = (const float*)d_in[2];
    const float* b1  = (const float*)d_in[3];
    const float* W2  = (const float*)d_in[4];
    const float* b2  = (const float*)d_in[5];
    const float* W3  = (const float*)d_in[6];
    const float* b3  = (const float*)d_in[7];
    float* out = (float*)d_out;

    // ws (~52 MB): cursor_rel | cnt | row_start | binned u32[NB<<14] 12.85MB |
    //   csr_src[NB<<14] 12.85MB | xb bf16 12.8MB | h1b bf16 12.8MB
    char* ws = (char*)d_ws;
    auto align = [](size_t v) { return (v + 255) & ~(size_t)255; };
    size_t o = 0;
    int* cursor_rel = (int*)(ws + o); o = align(o + 256 * 4);
    int* cnt       = (int*)(ws + o); o = align(o + (size_t)N_NODES * 4);
    int* row_start = (int*)(ws + o); o = align(o + (size_t)N_NODES * 4);
    unsigned* binned = (unsigned*)(ws + o); o = align(o + ((size_t)NB << CAPLOG) * 4);
    int* csr_src   = (int*)(ws + o); o = align(o + ((size_t)NB << CAPLOG) * 4);
    unsigned short* xb  = (unsigned short*)(ws + o); o = align(o + (size_t)N_NODES * 64 * 2);
    unsigned short* h1b = (unsigned short*)(ws + o); o = align(o + (size_t)N_NODES * 64 * 2);

    hipMemsetAsync(cursor_rel, 0, 256 * sizeof(int), stream);

    bin_pad_kernel<<<NBLK_A + PAD_BLOCKS, 256, 0, stream>>>(src, dst, cursor_rel,
                                                            binned, x, xb);
    bucket_fine<<<NB, 256, 0, stream>>>(binned, cursor_rel, cnt, row_start, csr_src);

    layer1_fused<<<N_NODES / 16, 256, 0, stream>>>(xb, csr_src, row_start, cnt,
                                                   W1, b1, h1b);
    layer23_fused<<<N_NODES / 16, 256, 0, stream>>>(h1b, csr_src, row_start, cnt,
                                                    W2, b2, W3, b3, out);
}

// Round 15
// 256.967 us; speedup vs baseline: 1.7950x; 1.7950x over previous
//
#include <hip/hip_runtime.h>
#include <hip/hip_bf16.h>

#define N_NODES 100000
#define N_EDGES 1600000
#define IN_CH 50
#define NPB 512                                   // nodes per bucket (dst >> 9)
#define NB ((N_NODES + NPB - 1) / NPB)            // 196 buckets
#define CAPLOG 14                                 // 16384 slots/bucket (max ~8.6K used)
#define EPB 4096
#define NBLK_A ((N_EDGES + EPB - 1) / EPB)        // 391 bin blocks
#define PAD_BLOCKS ((N_NODES * 64) / 1024)        // 6250 pad blocks (1024 thr)

// ---- 1. bin edges into fixed-capacity buckets (+ extra blocks: pad x->xb bf16) ----
// 1024 threads/block: 16 waves/block -> ~24 waves/CU during binning.
__global__ __launch_bounds__(1024) void bin_pad_kernel(
    const int* __restrict__ src, const int* __restrict__ dst,
    int* __restrict__ cursor_rel, unsigned* __restrict__ binned,
    const float* __restrict__ x, unsigned short* __restrict__ xb) {
    if (blockIdx.x >= NBLK_A) {                    // pad lane
        int t = (blockIdx.x - NBLK_A) * 1024 + threadIdx.x;  // < N_NODES*64
        int n = t >> 6, c = t & 63;
        float v = (c < IN_CH) ? x[n * IN_CH + c] : 0.0f;
        __hip_bfloat16 hb = __float2bfloat16(v);
        xb[t] = *(unsigned short*)&hb;
        return;
    }
    __shared__ int bc[NB];
    __shared__ int boff[NB];
    int t = threadIdx.x;
    if (t < NB) bc[t] = 0;
    __syncthreads();
    int e0 = blockIdx.x * EPB;
    int e1 = min(e0 + EPB, N_EDGES);
    for (int i = e0 + t; i < e1; i += 1024)
        atomicAdd(&bc[dst[i] >> 9], 1);
    __syncthreads();
    if (t < NB) {
        int v = bc[t];
        int rel = v ? atomicAdd(&cursor_rel[t], v) : 0;
        boff[t] = (t << CAPLOG) + rel;
        bc[t] = 0;                                 // reuse as local cursor
    }
    __syncthreads();
    for (int i = e0 + t; i < e1; i += 1024) {
        int d = dst[i];
        int b = d >> 9;
        int k = atomicAdd(&bc[b], 1);
        binned[boff[b] + k] = ((unsigned)(d & 511) << 17) | (unsigned)src[i];
    }
}

// ---- 2. per-bucket fine sort (u32 payload) -> cnt, row_start, csr_src ----
// 1024 threads/block: 196 blocks x 16 waves = ~12 waves/CU.
__global__ __launch_bounds__(1024) void bucket_fine(
    const unsigned* __restrict__ binned, const int* __restrict__ cursor_rel,
    int* __restrict__ cnt, int* __restrict__ row_start, int* __restrict__ csr_src) {
    __shared__ int lcnt[NPB];
    __shared__ int lofs[NPB];
    __shared__ int sc[NPB];
    int t = threadIdx.x;
    int b = blockIdx.x;
    int nbase = b * NPB;
    int bbase = b << CAPLOG;
    int ecnt  = cursor_rel[b];
    if (t < NPB) lcnt[t] = 0;
    __syncthreads();
    for (int i = t; i < ecnt; i += 1024)
        atomicAdd(&lcnt[(binned[bbase + i] >> 17) & 511], 1);
    __syncthreads();
    int v = (t < NPB) ? lcnt[t] : 0;
    if (t < NPB) sc[t] = v;
    __syncthreads();
    for (int off = 1; off < NPB; off <<= 1) {      // Hillis-Steele over 512
        int tmp = (t < NPB && t >= off) ? sc[t - off] : 0;
        __syncthreads();
        if (t < NPB) sc[t] += tmp;
        __syncthreads();
    }
    if (t < NPB) {
        int excl = sc[t] - v;
        lofs[t] = excl;
        int n = nbase + t;
        if (n < N_NODES) { cnt[n] = v; row_start[n] = bbase + excl; }
    }
    __syncthreads();
    for (int i = t; i < ecnt; i += 1024) {
        unsigned p = binned[bbase + i];
        int d = (int)((p >> 17) & 511);
        int k = atomicAdd(&lofs[d], 1);
        csr_src[bbase + k] = (int)(p & 0x1FFFFu);
    }
}

// unpack 8 bf16 from uint4, predicated fma into acc[0..8)
__device__ __forceinline__ void upadd8(float* a, uint4 v, float p) {
    a[0] = fmaf(p, __uint_as_float(v.x << 16), a[0]);
    a[1] = fmaf(p, __uint_as_float(v.x & 0xffff0000u), a[1]);
    a[2] = fmaf(p, __uint_as_float(v.y << 16), a[2]);
    a[3] = fmaf(p, __uint_as_float(v.y & 0xffff0000u), a[3]);
    a[4] = fmaf(p, __uint_as_float(v.z << 16), a[4]);
    a[5] = fmaf(p, __uint_as_float(v.z & 0xffff0000u), a[5]);
    a[6] = fmaf(p, __uint_as_float(v.w << 16), a[6]);
    a[7] = fmaf(p, __uint_as_float(v.w & 0xffff0000u), a[7]);
}

// wave-local LDS fence: LDS ops of one wave complete in order; no block barrier.
#define WAVE_LDS_FENCE() __asm__ volatile("s_waitcnt lgkmcnt(0)" ::: "memory")

// Gather-mean of 4 nodes per wave, chains interleaved (proven R7/R10/R13 shape).
__device__ __forceinline__ void gather4(
    const unsigned short* __restrict__ featb, const int* __restrict__ csr_src,
    const int* __restrict__ row_start, const int* __restrict__ cnt,
    int nb, int lane, float acc[4][8]) {
    int g  = lane >> 3;
    int cw = (lane & 7) * 8;
    int start[4], deg[4], sv[4];
    int dmax = 0;
    #pragma unroll
    for (int i = 0; i < 4; ++i) {
        start[i] = row_start[nb + i];
        deg[i]   = cnt[nb + i];
        dmax = max(dmax, deg[i]);
        #pragma unroll
        for (int c = 0; c < 8; ++c) acc[i][c] = 0.f;
    }
    #pragma unroll
    for (int i = 0; i < 4; ++i)
        sv[i] = (lane < deg[i]) ? csr_src[start[i] + lane] : 0;

    #pragma unroll
    for (int cb = 0; cb < 64; cb += 16) {
        if (cb >= dmax) break;                 // wave-uniform
        #pragma unroll
        for (int i = 0; i < 4; ++i) {
            int rem = deg[i] - cb;
            if (rem > 0) {                     // wave-uniform
                int s0 = __shfl(sv[i], cb + g);
                int s1 = __shfl(sv[i], cb + 8 + g);
                float p0 = (g < rem) ? 1.f : 0.f;
                float p1 = (g + 8 < rem) ? 1.f : 0.f;
                uint4 v0 = *(const uint4*)(featb + s0 * 64 + cw);
                uint4 v1 = *(const uint4*)(featb + s1 * 64 + cw);
                upadd8(acc[i], v0, p0);
                upadd8(acc[i], v1, p1);
            }
        }
    }
    if (dmax > 64) {                           // rare tail
        for (int i = 0; i < 4; ++i) {
            for (int c0 = 64; c0 < deg[i]; c0 += 64) {
                int rem = deg[i] - c0; if (rem > 64) rem = 64;
                int sx = (lane < rem) ? csr_src[start[i] + c0 + lane] : 0;
                for (int cb = 0; cb < rem; cb += 16) {
                    int s0 = __shfl(sx, cb + g);
                    int s1 = __shfl(sx, cb + 8 + g);
                    float p0 = (cb + g < rem) ? 1.f : 0.f;
                    float p1 = (cb + 8 + g < rem) ? 1.f : 0.f;
                    uint4 v0 = *(const uint4*)(featb + s0 * 64 + cw);
                    uint4 v1 = *(const uint4*)(featb + s1 * 64 + cw);
                    upadd8(acc[i], v0, p0);
                    upadd8(acc[i], v1, p1);
                }
            }
        }
    }
    #pragma unroll
    for (int i = 0; i < 4; ++i) {
        float inv = 1.0f / fmaxf((float)deg[i], 1.0f);
        #pragma unroll
        for (int c = 0; c < 8; ++c) {
            float t = acc[i][c];
            t += __shfl_xor(t, 8);
            t += __shfl_xor(t, 16);
            t += __shfl_xor(t, 32);
            acc[i][c] = t * inv;
        }
    }
}

__device__ __forceinline__ float bf16u(unsigned short u) {
    return __uint_as_float(((unsigned)u) << 16);
}

// ---- 3. layer 1 (R13-proven): 4 nodes/wave; gather(xb) + scalar-broadcast GEMM ----
__global__ __launch_bounds__(256) void layer1_fused(
    const unsigned short* __restrict__ xb,
    const int* __restrict__ csr_src, const int* __restrict__ row_start,
    const int* __restrict__ cnt, const float* __restrict__ W1,
    const float* __restrict__ b1, unsigned short* __restrict__ h1b) {
    int wv   = threadIdx.x >> 6;
    int lane = threadIdx.x & 63;
    int nb   = (blockIdx.x * 4 + wv) * 4;      // N_NODES % 16 == 0

    float acc[4][8];
    gather4(xb, csr_src, row_start, cnt, nb, lane, acc);

    __shared__ __align__(16) float selfF[4][4][64];
    __shared__ __align__(16) float meanF[4][4][64];
    #pragma unroll
    for (int i = 0; i < 4; ++i) {
        selfF[wv][i][lane] = bf16u(xb[((nb + i) << 6) + lane]);
        if (lane < 8) {
            *(float4*)&meanF[wv][i][lane * 8] =
                make_float4(acc[i][0], acc[i][1], acc[i][2], acc[i][3]);
            *(float4*)&meanF[wv][i][lane * 8 + 4] =
                make_float4(acc[i][4], acc[i][5], acc[i][6], acc[i][7]);
        }
    }
    WAVE_LDS_FENCE();

    float ao[4];
    float bb = b1[lane];
    #pragma unroll
    for (int i = 0; i < 4; ++i) ao[i] = bb;
    #pragma unroll
    for (int k = 0; k < IN_CH; ++k) {
        float w = W1[k * 64 + lane];           // lanes coalesced, reused x4
        #pragma unroll
        for (int i = 0; i < 4; ++i) ao[i] = fmaf(selfF[wv][i][k], w, ao[i]);
    }
    #pragma unroll
    for (int k = 0; k < IN_CH; ++k) {
        float w = W1[(IN_CH + k) * 64 + lane];
        #pragma unroll
        for (int i = 0; i < 4; ++i) ao[i] = fmaf(meanF[wv][i][k], w, ao[i]);
    }
    #pragma unroll
    for (int i = 0; i < 4; ++i) {
        float r = fmaxf(ao[i], 0.f);
        __hip_bfloat16 hb = __float2bfloat16(r);
        h1b[((nb + i) << 6) + lane] = *(unsigned short*)&hb;
    }
}

// ---- 4. layers 2+3 (R13-proven): gather(h1b) + scalar-broadcast GEMM + dot(W3) ----
__global__ __launch_bounds__(256) void layer23_fused(
    const unsigned short* __restrict__ h1b,
    const int* __restrict__ csr_src, const int* __restrict__ row_start,
    const int* __restrict__ cnt, const float* __restrict__ W2,
    const float* __restrict__ b2, const float* __restrict__ W3,
    const float* __restrict__ b3, float* __restrict__ out) {
    int wv   = threadIdx.x >> 6;
    int lane = threadIdx.x & 63;
    int nb   = (blockIdx.x * 4 + wv) * 4;

    float acc[4][8];
    gather4(h1b, csr_src, row_start, cnt, nb, lane, acc);

    __shared__ __align__(16) float featL[4][4][128];   // [0,64)=self, [64,128)=mean
    #pragma unroll
    for (int i = 0; i < 4; ++i) {
        featL[wv][i][lane] = bf16u(h1b[((nb + i) << 6) + lane]);
        if (lane < 8) {
            *(float4*)&featL[wv][i][64 + lane * 8] =
                make_float4(acc[i][0], acc[i][1], acc[i][2], acc[i][3]);
            *(float4*)&featL[wv][i][64 + lane * 8 + 4] =
                make_float4(acc[i][4], acc[i][5], acc[i][6], acc[i][7]);
        }
    }
    WAVE_LDS_FENCE();

    int hh = lane >> 5;                        // half-wave id: nodes nb+hh, nb+2+hh
    int j  = lane & 31;
    float a0 = b2[j], a1 = a0;
    #pragma unroll
    for (int k = 0; k < 128; ++k) {
        float w = W2[k * 32 + j];              // lanes coalesced, reused x2
        a0 = fmaf(featL[wv][hh][k],     w, a0);
        a1 = fmaf(featL[wv][2 + hh][k], w, a1);
    }
    float w3 = W3[j];
    float c3 = b3[0];
    float v0 = fmaxf(a0, 0.f) * w3;
    float v1 = fmaxf(a1, 0.f) * w3;
    #pragma unroll
    for (int off = 1; off <= 16; off <<= 1) {
        v0 += __shfl_xor(v0, off);
        v1 += __shfl_xor(v1, off);
    }
    if (j == 0) {
        out[nb + hh]     = v0 + c3;
        out[nb + 2 + hh] = v1 + c3;
    }
}

extern "C" void kernel_launch(void* const* d_in, const int* in_sizes, int n_in,
                              void* d_out, int out_size, void* d_ws, size_t ws_size,
                              hipStream_t stream) {
    const float* x   = (const float*)d_in[0];
    const int*   ei  = (const int*)d_in[1];
    const int*   src = ei;
    const int*   dst = ei + N_EDGES;
    const float* W1  = (const float*)d_in[2];
    const float* b1  = (const float*)d_in[3];
    const float* W2  = (const float*)d_in[4];
    const float* b2  = (const float*)d_in[5];
    const float* W3  = (const float*)d_in[6];
    const float* b3  = (const float*)d_in[7];
    float* out = (float*)d_out;

    // ws (~52 MB): cursor_rel | cnt | row_start | binned u32[NB<<14] 12.85MB |
    //   csr_src[NB<<14] 12.85MB | xb bf16 12.8MB | h1b bf16 12.8MB
    char* ws = (char*)d_ws;
    auto align = [](size_t v) { return (v + 255) & ~(size_t)255; };
    size_t o = 0;
    int* cursor_rel = (int*)(ws + o); o = align(o + 256 * 4);
    int* cnt       = (int*)(ws + o); o = align(o + (size_t)N_NODES * 4);
    int* row_start = (int*)(ws + o); o = align(o + (size_t)N_NODES * 4);
    unsigned* binned = (unsigned*)(ws + o); o = align(o + ((size_t)NB << CAPLOG) * 4);
    int* csr_src   = (int*)(ws + o); o = align(o + ((size_t)NB << CAPLOG) * 4);
    unsigned short* xb  = (unsigned short*)(ws + o); o = align(o + (size_t)N_NODES * 64 * 2);
    unsigned short* h1b = (unsigned short*)(ws + o); o = align(o + (size_t)N_NODES * 64 * 2);

    hipMemsetAsync(cursor_rel, 0, 256 * sizeof(int), stream);

    bin_pad_kernel<<<NBLK_A + PAD_BLOCKS, 1024, 0, stream>>>(src, dst, cursor_rel,
                                                             binned, x, xb);
    bucket_fine<<<NB, 1024, 0, stream>>>(binned, cursor_rel, cnt, row_start, csr_src);

    layer1_fused<<<N_NODES / 16, 256, 0, stream>>>(xb, csr_src, row_start, cnt,
                                                   W1, b1, h1b);
    layer23_fused<<<N_NODES / 16, 256, 0, stream>>>(h1b, csr_src, row_start, cnt,
                                                    W2, b2, W3, b3, out);
}